// Round 3
// baseline (754.534 us; speedup 1.0000x reference)
//
#include <hip/hip_runtime.h>
#include <cstdint>

// GridEncoder forward (torch-ngp semantics), MI355X.
// B = 1048576 points, D=3, L=16 levels, C=2, H=16, per_level_scale=2.0,
// log2_hashmap_size=19, align_corners=False.
//
// Level metadata:
//   res(l)   = 16 << l, scale(l) = res - 1
//   dense levels 0,1,2: offsets 0, 4920, 40864, base = res+1,
//     idx = cx + cy*base + cz*base^2
//   hashed levels 3..15: size 2^19, idx = hash & 0x7FFFF,
//     offset(l) = l*524288 - 1257368
//   primes (1, 2654435761, 805459861)
//
// R6 theory of record:
//  * Gather is L2-REQUEST-RATE bound: ~16 req/cy/XCD (16 L2 channels),
//    measured 0.4-0.5 req/cy/CU with VALU 11%, HBM 18%, occ 87% all idle.
//    R5's divergent pairing (if ix&1) executed both exec-masked paths
//    (12 load instrs) -> only -4.5%. Fix: BRANCHLESS UNIVERSAL PAIRING.
//    For every corner index g (global, region offsets all even), load the
//    aligned 16 B pair pr[g>>1] and select the half via g&1. For even-ix
//    lanes the two corner loads of a pair hit the SAME address -> L1/MSHR
//    merge, no L2 channel use. Works for dense levels too (g(c+1)=g(c)+1).
//    Uniform 8 x dwordx4 loads, no divergence. ~94M L2 requests -> floor
//    ~306 us (from 419).
//  * Transpose residual ~190 us for 268 MB (1.4 TB/s) regardless of LDS
//    vs direct structure -> outstanding-line (MSHR) x HBM-latency bound.
//    ws (128 MiB) fits L3 (256 MiB) but nt stores/loads bypassed it.
//    Fix: regular stores for ws in gather, regular loads in transpose
//    (nt only on streaming input loads and final out stores); 2 outputs
//    per thread to double per-wave line concurrency.

namespace {

using f32x2 = __attribute__((ext_vector_type(2))) float;
using f32x4 = __attribute__((ext_vector_type(4))) float;

// Global paired-corner indices for one level. g[c] is the GLOBAL entry
// index (region offset included, offsets all even).
__device__ __forceinline__ void level_indices(
    uint32_t ix, uint32_t iy, uint32_t iz, uint32_t l, uint32_t g[8]) {
  if (l >= 3u) {
    uint32_t off = l * 524288u - 1257368u;        // even
    const uint32_t P2 = 2654435761u, P3 = 805459861u;
    uint32_t hy0 = iy * P2, hy1 = hy0 + P2;
    uint32_t hz0 = iz * P3, hz1 = hz0 + P3;
    uint32_t hb[4] = {hy0 ^ hz0, hy1 ^ hz0, hy0 ^ hz1, hy1 ^ hz1};
    uint32_t ix1 = ix + 1u;
#pragma unroll
    for (int j = 0; j < 4; ++j) {
      g[2 * j]     = ((ix  ^ hb[j]) & 0x7FFFFu) + off;
      g[2 * j + 1] = ((ix1 ^ hb[j]) & 0x7FFFFu) + off;
    }
  } else {
    uint32_t off = (l == 0u) ? 0u : ((l == 1u) ? 4920u : 40864u);  // even
    uint32_t base = (16u << l) + 1u;
    uint32_t bb = base * base;
    uint32_t dy0 = iy * base, dy1 = dy0 + base;
    uint32_t dz0 = iz * bb,   dz1 = dz0 + bb;
#pragma unroll
    for (int c = 0; c < 8; ++c) {
      g[c] = ix + (uint32_t)(c & 1) +
             ((c & 2) ? dy1 : dy0) + ((c & 4) ? dz1 : dz0) + off;
    }
  }
}

// ---- Pass 1: level-phased gather, writes level-major ws[l*B + p] ----
__global__ __launch_bounds__(256) void gather_lm_kernel(
    const float* __restrict__ in,      // [B,3] in [-1,1]
    const f32x2* __restrict__ emb,     // [7131240] float2
    f32x2* __restrict__ ws,            // [16*B] float2, level-major
    uint32_t B) {
  uint32_t l = blockIdx.y;                       // level: slowest dispatch dim
  uint32_t p = blockIdx.x * 256u + threadIdx.x;  // point
  if (p >= B) return;

  // streaming input: nontemporal (read-once, keep out of caches)
  float x = (__builtin_nontemporal_load(&in[p * 3 + 0]) + 1.0f) * 0.5f;
  float y = (__builtin_nontemporal_load(&in[p * 3 + 1]) + 1.0f) * 0.5f;
  float z = (__builtin_nontemporal_load(&in[p * 3 + 2]) + 1.0f) * 0.5f;

  uint32_t res = 16u << l;
  float scale = (float)res - 1.0f;
  float px = x * scale + 0.5f;
  float py = y * scale + 0.5f;
  float pz = z * scale + 0.5f;
  float gx = floorf(px), gy = floorf(py), gz = floorf(pz);
  float rx = px - gx, ry = py - gy, rz = pz - gz;
  uint32_t ix = (uint32_t)gx, iy = (uint32_t)gy, iz = (uint32_t)gz;

  uint32_t g[8];
  level_indices(ix, iy, iz, l, g);

  // Branchless paired gather: 16 B aligned pair containing entry g[c].
  // Pair base g&~1 never crosses a region boundary (offsets even, region
  // sizes even), so loads are always in-bounds and 16 B aligned.
  const f32x4* __restrict__ pr = reinterpret_cast<const f32x4*>(emb);
  f32x2 e[8];
#pragma unroll
  for (int c = 0; c < 8; ++c) {
    f32x4 v = pr[g[c] >> 1];
    f32x2 lo; lo.x = v.x; lo.y = v.y;
    f32x2 hi; hi.x = v.z; hi.y = v.w;
    e[c] = (g[c] & 1u) ? hi : lo;
  }

  float wx1 = rx, wx0 = 1.0f - rx;
  float wy1 = ry, wy0 = 1.0f - ry;
  float wz1 = rz, wz0 = 1.0f - rz;

  float o0 = 0.0f, o1 = 0.0f;
#pragma unroll
  for (int c = 0; c < 8; ++c) {
    float w = ((c & 1) ? wx1 : wx0) *
              ((c & 2) ? wy1 : wy0) *
              ((c & 4) ? wz1 : wz0);
    o0 = fmaf(w, e[c].x, o0);
    o1 = fmaf(w, e[c].y, o1);
  }

  f32x2 r; r.x = o0; r.y = o1;
  ws[(size_t)l * B + p] = r;   // REGULAR store: let ws land in L2/L3 for pass 2
}

// ---- Pass 2: transpose level-major ws -> point-major out ----
// One thread per TWO output float4s (t and t+B*4), doubling per-wave
// outstanding cache lines (the pass is line-concurrency x latency bound).
// Loads are REGULAR (ws should be L3-resident); stores nt (write-once).
__global__ __launch_bounds__(256) void transpose_kernel(
    const f32x2* __restrict__ ws,   // [16*B] level-major
    f32x4* __restrict__ out,        // [B*8] float4 == [B,16,2] floats
    uint32_t B) {
  uint32_t half = B * 4u;
  uint32_t t = blockIdx.x * 256u + threadIdx.x;
  if (t >= half) return;
  uint32_t o0 = t, o1 = t + half;
  uint32_t j0 = o0 & 7u, q0 = o0 >> 3;
  uint32_t j1 = o1 & 7u, q1 = o1 >> 3;

  f32x2 a0 = ws[(size_t)(2u * j0)      * B + q0];
  f32x2 b0 = ws[(size_t)(2u * j0 + 1u) * B + q0];
  f32x2 a1 = ws[(size_t)(2u * j1)      * B + q1];
  f32x2 b1 = ws[(size_t)(2u * j1 + 1u) * B + q1];

  f32x4 v0; v0.x = a0.x; v0.y = a0.y; v0.z = b0.x; v0.w = b0.y;
  f32x4 v1; v1.x = a1.x; v1.y = a1.y; v1.z = b1.x; v1.w = b1.y;
  __builtin_nontemporal_store(v0, &out[o0]);
  __builtin_nontemporal_store(v1, &out[o1]);
}

// ---- Fallback (ws too small): single-pass kernel ----
__global__ __launch_bounds__(256) void grid_encode_fallback(
    const float* __restrict__ in, const f32x2* __restrict__ emb,
    f32x4* __restrict__ out, uint32_t B) {
  uint32_t p = blockIdx.x * 256u + threadIdx.x;
  if (p >= B) return;
  float x = (in[p * 3 + 0] + 1.0f) * 0.5f;
  float y = (in[p * 3 + 1] + 1.0f) * 0.5f;
  float z = (in[p * 3 + 2] + 1.0f) * 0.5f;
  const f32x4* __restrict__ pr = reinterpret_cast<const f32x4*>(emb);
#pragma unroll 1
  for (uint32_t l = 0; l < 16u; ++l) {
    uint32_t res = 16u << l;
    float scale = (float)res - 1.0f;
    float px = x * scale + 0.5f;
    float py = y * scale + 0.5f;
    float pz = z * scale + 0.5f;
    float gx = floorf(px), gy = floorf(py), gz = floorf(pz);
    float rx = px - gx, ry = py - gy, rz = pz - gz;
    uint32_t ix = (uint32_t)gx, iy = (uint32_t)gy, iz = (uint32_t)gz;
    uint32_t g[8];
    level_indices(ix, iy, iz, l, g);
    f32x2 e[8];
#pragma unroll
    for (int c = 0; c < 8; ++c) {
      f32x4 v = pr[g[c] >> 1];
      f32x2 lo; lo.x = v.x; lo.y = v.y;
      f32x2 hi; hi.x = v.z; hi.y = v.w;
      e[c] = (g[c] & 1u) ? hi : lo;
    }
    float wx1 = rx, wx0 = 1.0f - rx;
    float wy1 = ry, wy0 = 1.0f - ry;
    float wz1 = rz, wz0 = 1.0f - rz;
    float o0 = 0.0f, o1 = 0.0f;
#pragma unroll
    for (int c = 0; c < 8; ++c) {
      float w = ((c & 1) ? wx1 : wx0) *
                ((c & 2) ? wy1 : wy0) *
                ((c & 4) ? wz1 : wz0);
      o0 = fmaf(w, e[c].x, o0);
      o1 = fmaf(w, e[c].y, o1);
    }
    // scalar f32x2 store into [B,16,2]
    f32x2 r; r.x = o0; r.y = o1;
    reinterpret_cast<f32x2*>(out)[(size_t)p * 16u + l] = r;
  }
}

}  // namespace

extern "C" void kernel_launch(void* const* d_in, const int* in_sizes, int n_in,
                              void* d_out, int out_size, void* d_ws, size_t ws_size,
                              hipStream_t stream) {
  (void)n_in; (void)out_size;
  const float* in = (const float*)d_in[0];
  const f32x2* emb = (const f32x2*)d_in[1];
  f32x4* out = (f32x4*)d_out;
  uint32_t B = (uint32_t)(in_sizes[0] / 3);
  uint32_t pblocks = (B + 255u) / 256u;

  size_t ws_needed = (size_t)16 * B * sizeof(f32x2);   // 128 MiB at B=1M
  if (ws_size >= ws_needed) {
    f32x2* ws = (f32x2*)d_ws;
    hipLaunchKernelGGL(gather_lm_kernel, dim3(pblocks, 16), dim3(256), 0,
                       stream, in, emb, ws, B);
    uint32_t tblocks = (B * 4u + 255u) / 256u;
    hipLaunchKernelGGL(transpose_kernel, dim3(tblocks), dim3(256), 0,
                       stream, ws, out, B);
  } else {
    hipLaunchKernelGGL(grid_encode_fallback, dim3(pblocks), dim3(256), 0,
                       stream, in, emb, out, B);
  }
}

// Round 4
// 599.060 us; speedup vs baseline: 1.2595x; 1.2595x over previous
//
#include <hip/hip_runtime.h>
#include <cstdint>

// GridEncoder forward (torch-ngp semantics), MI355X.
// B = 1048576 points, D=3, L=16 levels, C=2, H=16, per_level_scale=2.0,
// log2_hashmap_size=19, align_corners=False.
//
// Level metadata:
//   res(l)   = 16 << l, scale(l) = res - 1
//   dense levels 0,1,2: offsets 0, 4920, 40864, base = res+1,
//     idx = cx + cy*base + cz*base^2
//   hashed levels 3..15: size 2^19, idx = hash & 0x7FFFF,
//     offset(l) = l*524288 - 1257368
//   primes (1, 2654435761, 805459861)
//
// R7 theory of record (post-mortems R5/R6):
//  * R6 FAILED (-24%): regular ws stores evicted the L2-resident hash
//    tables (FETCH +15%); universal 16 B pairing never reduced request
//    count (odd-ix lanes still need 8 loads). Both reverted.
//  * Request-rate model DEAD: R5 cut requests 25% -> only -4.5% time.
//    Surviving model: WAVE-LIFETIME limit. Gather waves are short
//    straight-line code; lifetime = nt-in-load (~900 cy HBM) + addr math
//    + gather (~250 cy L2) + FMA. 28 waves/CU / ~1700 cy * 64 pts =
//    throughput matching the observed 419 us.
//  * R7 levers: (1) pass 0 normalizes in -> planar X,Y,Z (12 MiB,
//    L2/L3-hot across all 16 bands): head-of-chain 900->~300 cy and
//    -192 MB HBM re-reads. (2) 2 points/thread software-pipelined
//    (issue A gathers, issue B gathers, then consume A): half the waves,
//    2x outstanding misses each. (3) ws stores nontemporal (R6 lesson).
//    (4) transpose: 16 B loads/stores, 2 outputs/thread.

namespace {

using f32x2 = __attribute__((ext_vector_type(2))) float;
using f32x4 = __attribute__((ext_vector_type(4))) float;

// Global corner indices + interp factors for one level.
__device__ __forceinline__ void level_setup_g(
    float x, float y, float z, uint32_t l,
    uint32_t g[8], float f[6]) {
  uint32_t res = 16u << l;
  float scale = (float)res - 1.0f;
  float px = x * scale + 0.5f;
  float py = y * scale + 0.5f;
  float pz = z * scale + 0.5f;
  float gx = floorf(px), gy = floorf(py), gz = floorf(pz);
  float rx = px - gx, ry = py - gy, rz = pz - gz;
  uint32_t ix = (uint32_t)gx, iy = (uint32_t)gy, iz = (uint32_t)gz;

  if (l >= 3u) {
    uint32_t off = l * 524288u - 1257368u;
    const uint32_t P2 = 2654435761u, P3 = 805459861u;
    uint32_t hy0 = iy * P2, hy1 = hy0 + P2;
    uint32_t hz0 = iz * P3, hz1 = hz0 + P3;
    uint32_t hb[4] = {hy0 ^ hz0, hy1 ^ hz0, hy0 ^ hz1, hy1 ^ hz1};
    uint32_t ix1 = ix + 1u;
#pragma unroll
    for (int j = 0; j < 4; ++j) {
      g[2 * j]     = ((ix  ^ hb[j]) & 0x7FFFFu) + off;
      g[2 * j + 1] = ((ix1 ^ hb[j]) & 0x7FFFFu) + off;
    }
  } else {
    uint32_t off = (l == 0u) ? 0u : ((l == 1u) ? 4920u : 40864u);
    uint32_t base = res + 1u;
    uint32_t bb = base * base;
    uint32_t dy0 = iy * base, dy1 = dy0 + base;
    uint32_t dz0 = iz * bb,   dz1 = dz0 + bb;
#pragma unroll
    for (int c = 0; c < 8; ++c) {
      g[c] = ix + (uint32_t)(c & 1) +
             ((c & 2) ? dy1 : dy0) + ((c & 4) ? dz1 : dz0) + off;
    }
  }
  f[0] = 1.0f - rx; f[1] = rx;
  f[2] = 1.0f - ry; f[3] = ry;
  f[4] = 1.0f - rz; f[5] = rz;
}

__device__ __forceinline__ f32x2 interp8(const f32x2 e[8], const float f[6]) {
  float o0 = 0.0f, o1 = 0.0f;
#pragma unroll
  for (int c = 0; c < 8; ++c) {
    float w = f[c & 1] * f[2 + ((c >> 1) & 1)] * f[4 + ((c >> 2) & 1)];
    o0 = fmaf(w, e[c].x, o0);
    o1 = fmaf(w, e[c].y, o1);
  }
  f32x2 r; r.x = o0; r.y = o1;
  return r;
}

// ---- Pass 0: normalize inputs into planar X,Y,Z (L2/L3-hot, 12 MiB) ----
__global__ __launch_bounds__(256) void prep_xyz_kernel(
    const float* __restrict__ in,    // [B,3] in [-1,1]
    float* __restrict__ X, float* __restrict__ Y, float* __restrict__ Z,
    uint32_t B) {
  uint32_t t = blockIdx.x * 256u + threadIdx.x;
  uint32_t nquad = B >> 2;          // B % 4 == 0 guaranteed by launcher
  if (t >= nquad) return;
  const f32x4* in4 = reinterpret_cast<const f32x4*>(in);
  f32x4 q0 = __builtin_nontemporal_load(&in4[t * 3 + 0]);
  f32x4 q1 = __builtin_nontemporal_load(&in4[t * 3 + 1]);
  f32x4 q2 = __builtin_nontemporal_load(&in4[t * 3 + 2]);
  f32x4 xv = {q0.x, q0.w, q1.z, q2.y};
  f32x4 yv = {q0.y, q1.x, q1.w, q2.z};
  f32x4 zv = {q0.z, q1.y, q2.x, q2.w};
  xv = (xv + 1.0f) * 0.5f;
  yv = (yv + 1.0f) * 0.5f;
  zv = (zv + 1.0f) * 0.5f;
  reinterpret_cast<f32x4*>(X)[t] = xv;   // regular stores: keep cached
  reinterpret_cast<f32x4*>(Y)[t] = yv;
  reinterpret_cast<f32x4*>(Z)[t] = zv;
}

// ---- Pass 1: level-phased gather, 2 points/thread, pipelined ----
template <bool XYZ>
__global__ __launch_bounds__(256, 6) void gather_lm_kernel(
    const float* __restrict__ in,
    const float* __restrict__ X, const float* __restrict__ Y,
    const float* __restrict__ Z,
    const f32x2* __restrict__ emb,     // [7131240] float2
    f32x2* __restrict__ ws,            // [16*B] float2, level-major
    uint32_t B) {
  uint32_t l = blockIdx.y;
  uint32_t p0 = blockIdx.x * 512u + threadIdx.x;
  uint32_t p1 = p0 + 256u;
  bool vA = p0 < B, vB = p1 < B;
  if (!vA) return;
  uint32_t p1c = vB ? p1 : p0;       // clamp (recomputed, result discarded)

  float xA, yA, zA, xB, yB, zB;
  if (XYZ) {
    xA = X[p0]; yA = Y[p0]; zA = Z[p0];
    xB = X[p1c]; yB = Y[p1c]; zB = Z[p1c];
  } else {
    xA = (__builtin_nontemporal_load(&in[p0 * 3 + 0]) + 1.0f) * 0.5f;
    yA = (__builtin_nontemporal_load(&in[p0 * 3 + 1]) + 1.0f) * 0.5f;
    zA = (__builtin_nontemporal_load(&in[p0 * 3 + 2]) + 1.0f) * 0.5f;
    xB = (__builtin_nontemporal_load(&in[p1c * 3 + 0]) + 1.0f) * 0.5f;
    yB = (__builtin_nontemporal_load(&in[p1c * 3 + 1]) + 1.0f) * 0.5f;
    zB = (__builtin_nontemporal_load(&in[p1c * 3 + 2]) + 1.0f) * 0.5f;
  }

  // --- issue A gathers ---
  uint32_t gA[8]; float fA[6];
  level_setup_g(xA, yA, zA, l, gA, fA);
  f32x2 eA[8];
#pragma unroll
  for (int c = 0; c < 8; ++c) eA[c] = emb[gA[c]];

  // --- issue B gathers (overlaps A's latency) ---
  uint32_t gB[8]; float fB[6];
  level_setup_g(xB, yB, zB, l, gB, fB);
  f32x2 eB[8];
#pragma unroll
  for (int c = 0; c < 8; ++c) eB[c] = emb[gB[c]];

  // --- consume A, then B ---
  f32x2 rA = interp8(eA, fA);
  __builtin_nontemporal_store(rA, &ws[(size_t)l * B + p0]);
  if (vB) {
    f32x2 rB = interp8(eB, fB);
    __builtin_nontemporal_store(rB, &ws[(size_t)l * B + p1]);
  }
}

// ---- Pass 2: transpose level-major ws -> point-major out ----
// Thread t: j = t&7, point pair q0 = 2*(t>>3). Two f32x4 loads (rows 2j,
// 2j+1, 16 B aligned since q0 even) -> two f32x4 outputs (points q0,q0+1).
// Per store instruction each lane-octet writes 128 B contiguous (full
// lines); loads per wave form 8 x 128 B contiguous segments.
__global__ __launch_bounds__(256) void transpose_kernel(
    const f32x2* __restrict__ ws,   // [16*B] level-major
    f32x4* __restrict__ out,        // [B*8] float4 == [B,16,2] floats
    uint32_t B) {
  uint32_t n = (B >> 1) * 8u;        // B % 2 == 0 guaranteed by launcher
  uint32_t t = blockIdx.x * 256u + threadIdx.x;
  if (t >= n) return;
  uint32_t j = t & 7u;
  uint32_t q0 = (t >> 3) * 2u;
  const f32x4* ws4 = reinterpret_cast<const f32x4*>(ws);
  f32x4 va = ws4[((size_t)(2u * j)      * B + q0) >> 1];
  f32x4 vb = ws4[((size_t)(2u * j + 1u) * B + q0) >> 1];
  f32x4 v0 = {va.x, va.y, vb.x, vb.y};
  f32x4 v1 = {va.z, va.w, vb.z, vb.w};
  __builtin_nontemporal_store(v0, &out[(size_t)q0 * 8u + j]);
  __builtin_nontemporal_store(v1, &out[(size_t)(q0 + 1u) * 8u + j]);
}

// ---- Fallback (ws too small / odd B): single-pass kernel ----
__global__ __launch_bounds__(256) void grid_encode_fallback(
    const float* __restrict__ in, const f32x2* __restrict__ emb,
    f32x2* __restrict__ out, uint32_t B) {
  uint32_t p = blockIdx.x * 256u + threadIdx.x;
  if (p >= B) return;
  float x = (in[p * 3 + 0] + 1.0f) * 0.5f;
  float y = (in[p * 3 + 1] + 1.0f) * 0.5f;
  float z = (in[p * 3 + 2] + 1.0f) * 0.5f;
#pragma unroll 1
  for (uint32_t l = 0; l < 16u; ++l) {
    uint32_t g[8]; float f[6];
    level_setup_g(x, y, z, l, g, f);
    f32x2 e[8];
#pragma unroll
    for (int c = 0; c < 8; ++c) e[c] = emb[g[c]];
    out[(size_t)p * 16u + l] = interp8(e, f);
  }
}

}  // namespace

extern "C" void kernel_launch(void* const* d_in, const int* in_sizes, int n_in,
                              void* d_out, int out_size, void* d_ws, size_t ws_size,
                              hipStream_t stream) {
  (void)n_in; (void)out_size;
  const float* in = (const float*)d_in[0];
  const f32x2* emb = (const f32x2*)d_in[1];
  uint32_t B = (uint32_t)(in_sizes[0] / 3);

  size_t ws_lm   = (size_t)16 * B * sizeof(f32x2);          // 128 MiB at B=1M
  size_t ws_full = ws_lm + (size_t)3 * B * sizeof(float);   // + 12 MiB xyz

  if ((B % 4u) == 0u && ws_size >= ws_lm) {
    f32x2* ws = (f32x2*)d_ws;
    uint32_t gblocks = (B + 511u) / 512u;
    bool use_xyz = ws_size >= ws_full;
    if (use_xyz) {
      float* X = (float*)((char*)d_ws + ws_lm);
      float* Y = X + B;
      float* Z = Y + B;
      uint32_t pblocks = ((B >> 2) + 255u) / 256u;
      hipLaunchKernelGGL(prep_xyz_kernel, dim3(pblocks), dim3(256), 0, stream,
                         in, X, Y, Z, B);
      hipLaunchKernelGGL((gather_lm_kernel<true>), dim3(gblocks, 16), dim3(256),
                         0, stream, in, X, Y, Z, emb, ws, B);
    } else {
      hipLaunchKernelGGL((gather_lm_kernel<false>), dim3(gblocks, 16), dim3(256),
                         0, stream, in, nullptr, nullptr, nullptr, emb, ws, B);
    }
    uint32_t tblocks = ((B >> 1) * 8u + 255u) / 256u;
    hipLaunchKernelGGL(transpose_kernel, dim3(tblocks), dim3(256), 0, stream,
                       ws, (f32x4*)d_out, B);
  } else {
    uint32_t pblocks = (B + 255u) / 256u;
    hipLaunchKernelGGL(grid_encode_fallback, dim3(pblocks), dim3(256), 0,
                       stream, in, emb, (f32x2*)d_out, B);
  }
}